// Round 11
// baseline (506.230 us; speedup 1.0000x reference)
//
#include <hip/hip_runtime.h>
#include <stdint.h>

#define NB 8
#define NC 256
#define NE 128
#define NHW 4096

typedef __bf16 v8bf __attribute__((ext_vector_type(8)));
typedef float v4f __attribute__((ext_vector_type(4)));
typedef float v16f __attribute__((ext_vector_type(16)));
typedef unsigned int v4u __attribute__((ext_vector_type(4)));

typedef unsigned int __attribute__((address_space(1))) uint_g;
typedef unsigned int __attribute__((address_space(3))) uint_l;

#if __has_builtin(__builtin_amdgcn_exp2f)
#define EXP2F(x) __builtin_amdgcn_exp2f(x)
#else
#define EXP2F(x) exp2f(x)
#endif

// LDS-only barrier: drains lgkmcnt but NOT vmcnt (global prefetch/DMA stays in flight)
#define BARRIER_LDS() asm volatile("s_waitcnt lgkmcnt(0)\n\ts_barrier" ::: "memory")
#define WAIT_VM0()    asm volatile("s_waitcnt vmcnt(0)" ::: "memory")

// async global->LDS DMA, 16B per lane: LDS dst = uniform base + lane*16
__device__ __forceinline__ void dma16(const unsigned short* g, unsigned short* l) {
    __builtin_amdgcn_global_load_lds((const uint_g*)g, (uint_l*)l, 16, 0, 0);
}

// fp32 -> bf16 round-to-nearest-even
__device__ __forceinline__ unsigned short f2bf(float x) {
    union { float f; unsigned int u; } v; v.f = x;
    unsigned int r = v.u + 0x7fffu + ((v.u >> 16) & 1u);
    return (unsigned short)(r >> 16);
}

// pack two fp32 -> bf16x2, round-half-up (P in (0,1], R4-verified accuracy)
__device__ __forceinline__ unsigned int pack_bf2_ru(float a, float b) {
    union { float f; unsigned int u; } va, vb; va.f = a; vb.f = b;
    return ((va.u + 0x8000u) >> 16) | ((vb.u + 0x8000u) & 0xffff0000u);
}

// ---------------- K0: cast weights. Wbf[e][c], e<128 = w_theta*(scale*log2e), e>=128 = w_phi
__global__ __launch_bounds__(256) void cast_w_kernel(const float* __restrict__ wt,
                                                     const float* __restrict__ wp,
                                                     unsigned short* __restrict__ Wbf) {
    int i = blockIdx.x * 256 + threadIdx.x;
    const float QS = 0.08838834764831845f * 1.4426950408889634f;
    float v = (i < 32768) ? wt[i] * QS : wp[i - 32768];
    Wbf[i] = f2bf(v);
}

// ---------------- K1: projection (+ fused V cast). K stored PRE-SWIZZLED
// (16B unit u -> u ^ (row&15) within each row) so attn's DMA'd LDS tile is
// conflict-free under the R5-verified fragment reads. Q unswizzled.
__global__ __launch_bounds__(256, 2) void proj_kernel(const float* __restrict__ l,
                                                      const unsigned short* __restrict__ Wbf,
                                                      unsigned short* __restrict__ Qbf,
                                                      unsigned short* __restrict__ Kbf,
                                                      unsigned short* __restrict__ Vbf) {
    __shared__ __align__(16) unsigned short A[64][264];
    __shared__ __align__(16) unsigned short Ost[2][32][136];
    const int tid = threadIdx.x;
    const int b = blockIdx.x & 7;
    const int qt = (blockIdx.x >> 3) << 6;
    const float* lb = l + ((size_t)b * NC * NHW + qt);

    for (int s = 0; s < 16; ++s) {
        int f = tid + s * 256;
        int c = f >> 4, j = f & 15;
        float4 v = *(const float4*)(lb + (size_t)c * NHW + j * 4);
        ushort4 o4;
        o4.x = f2bf(v.x); o4.y = f2bf(v.y); o4.z = f2bf(v.z); o4.w = f2bf(v.w);
        A[j * 4 + 0][c] = o4.x;
        A[j * 4 + 1][c] = o4.y;
        A[j * 4 + 2][c] = o4.z;
        A[j * 4 + 3][c] = o4.w;
        *(ushort4*)(Vbf + (size_t)b * NC * NHW + (size_t)c * NHW + qt + j * 4) = o4;
    }
    __syncthreads();

    const int w = tid >> 6, L = tid & 63;
    const int l15 = L & 15, q4 = L >> 4;
    const v4f vz = {0.f, 0.f, 0.f, 0.f};
    v4f acc[4][4];
    for (int mt = 0; mt < 4; ++mt)
        for (int nt = 0; nt < 4; ++nt) acc[mt][nt] = vz;

    for (int kf = 0; kf < 8; ++kf) {
        int kc = kf * 32 + q4 * 8;
        v8bf a[4], bb[4];
        for (int mt = 0; mt < 4; ++mt)
            a[mt] = *(const v8bf*)&A[mt * 16 + l15][kc];
        for (int nt = 0; nt < 4; ++nt)
            bb[nt] = *(const v8bf*)(Wbf + (w * 64 + nt * 16 + l15) * 256 + kc);
        for (int mt = 0; mt < 4; ++mt)
            for (int nt = 0; nt < 4; ++nt)
                acc[mt][nt] = __builtin_amdgcn_mfma_f32_16x16x32_bf16(a[mt], bb[nt], acc[mt][nt], 0, 0, 0);
    }

    const int side = w >> 1;
    const int ebase = (w & 1) * 64;
#pragma unroll
    for (int ph = 0; ph < 2; ++ph) {
        __syncthreads();
#pragma unroll
        for (int mh = 0; mh < 2; ++mh) {
            int mt = ph * 2 + mh;
#pragma unroll
            for (int nt = 0; nt < 4; ++nt)
#pragma unroll
                for (int r = 0; r < 4; ++r) {
                    int q32 = mh * 16 + q4 * 4 + r;
                    Ost[side][q32][ebase + nt * 16 + l15] = f2bf(acc[mt][nt][r]);
                }
        }
        __syncthreads();
#pragma unroll
        for (int s = 0; s < 4; ++s) {
            int idx = tid + s * 256;
            int sd = idx >> 9, rem = idx & 511;
            int r32 = rem >> 4, c8 = rem & 15;
            unsigned short* dst = sd ? Kbf : Qbf;
            int c8s = sd ? (c8 ^ (r32 & 15)) : c8;   // pre-swizzle K only
            *(uint4*)(dst + ((size_t)b * NHW + qt + ph * 32 + r32) * NE + c8s * 8) =
                *(const uint4*)&Ost[sd][r32][c8 * 8];
        }
    }
}

// ---------------- K2: flash attention, producer/consumer, 2 DECOUPLED blocks/CU.
// Identical to R10 except the ONE bug fix: Pu buffer stride is 4096 shorts
// (8KB = 8 frag-tiles x 1KB), not 8192. R10's 8192-short stride pushed buf 1
// out of the shared-memory allocation -> odd k-tiles' P lost -> absmax 0.256.
// Block 256 thr = 4 waves (2P + 2C), q-tile 64, k-tile 64, grid 512 -> 2
// blocks/CU with independent barrier domains; roles XORed by (blockIdx>>8)&1.
// LDS 48.3K: Ku dbuf 32K | Pu dbuf 16K | lsum 256B. 1 LDS-only barrier/round.
__global__ __launch_bounds__(256, 2) void attn_kernel(const unsigned short* __restrict__ Qbf,
                                                      const unsigned short* __restrict__ Kbf,
                                                      const unsigned short* __restrict__ Vbf,
                                                      float* __restrict__ out) {
    __shared__ __align__(16) unsigned char smem[49408];
    unsigned short* KuS = (unsigned short*)smem;             // 2 x 16KB swizzled K tiles
    unsigned short* PuS = (unsigned short*)(smem + 32768);   // 2 bufs x 8 frag-tiles x 1KB
    float* lsumF = (float*)(smem + 49152);                   // [2][32]

    const int tid = threadIdx.x;
    const int b = blockIdx.x & 7;                            // batch -> XCD affinity
    const int qt64 = (blockIdx.x >> 3) << 6;
    const int w = tid >> 6;
    const int L = tid & 63;
    const int l31 = L & 31, hi = L >> 5;
    const int x15 = l31 & 15;
    const int rw = w ^ (((blockIdx.x >> 8) & 1) << 1);       // role-mix co-resident blocks
    const bool isP = rw < 2;
    const int pi = rw & 1;                                   // producer q-slice / consumer c-half

    const unsigned short* Kb = Kbf + (size_t)b * NHW * NE;
    const unsigned short* Vb = Vbf + (size_t)b * NC * NHW;

    v16f o[4][2];                                            // consumer acc [ct][qt], 128 AGPR
#pragma unroll
    for (int ct = 0; ct < 4; ++ct)
#pragma unroll
        for (int qt = 0; qt < 2; ++qt)
#pragma unroll
            for (int r = 0; r < 16; ++r) o[ct][qt][r] = 0.f;
    float lacc = 0.f;                                        // producer row-sum partial

    v8bf bq[8];                                              // producer Q B-frags
    v8bf av[4][4];                                           // consumer V A-frags [ct][kf]
    const unsigned short* vbase[4];

    if (isP) {
        // producer prologue: Q frags + DMA K tile 0 into buf 0 (8 x 1KB per wave)
        const unsigned short* qrow = Qbf + ((size_t)b * NHW + qt64 + pi * 32 + l31) * NE + hi * 8;
#pragma unroll
        for (int ef = 0; ef < 8; ++ef)
            bq[ef] = *(const v8bf*)(qrow + ef * 16);
#pragma unroll
        for (int jj = 0; jj < 8; ++jj) {
            int j = pi * 8 + jj;
            dma16(Kb + (size_t)j * 512 + L * 8, KuS + j * 512);
        }
        WAIT_VM0();
    } else {
        // consumer prologue: V frag bases + tile-0 frags
#pragma unroll
        for (int ct = 0; ct < 4; ++ct) {
            vbase[ct] = Vb + (size_t)(pi * 128 + ct * 32 + l31) * NHW + hi * 8;
#pragma unroll
            for (int kf = 0; kf < 4; ++kf)
                av[ct][kf] = *(const v8bf*)(vbase[ct] + kf * 16);
        }
    }
    BARRIER_LDS();

    for (int it = 0; it < 65; ++it) {
        if (isP && it < 64) {
            // ================= PRODUCER round i =================
            const int buf = it & 1;
            const int nbuf = (it + 1) & 1;
            const size_t ktn = (size_t)((it + 1) & 63) * 64;
#pragma unroll
            for (int jj = 0; jj < 8; ++jj) {
                int j = pi * 8 + jj;
                dma16(Kb + ktn * NE + (size_t)j * 512 + L * 8, KuS + nbuf * 8192 + j * 512);
            }
            const unsigned short* kub = KuS + buf * 8192;
#pragma unroll
            for (int kt = 0; kt < 2; ++kt) {
                v16f sa, sb;
#pragma unroll
                for (int r = 0; r < 16; ++r) { sa[r] = 0.f; sb[r] = 0.f; }
                const unsigned short* krow = kub + (kt * 32 + l31) * 128;
#pragma unroll
                for (int ef = 0; ef < 4; ++ef) {
                    v8bf ak0 = *(const v8bf*)(krow + (((2 * ef + hi) ^ x15) * 8));
                    v8bf ak1 = *(const v8bf*)(krow + (((2 * (ef + 4) + hi) ^ x15) * 8));
                    sa = __builtin_amdgcn_mfma_f32_32x32x16_bf16(ak0, bq[ef], sa, 0, 0, 0);
                    sb = __builtin_amdgcn_mfma_f32_32x32x16_bf16(ak1, bq[ef + 4], sb, 0, 0, 0);
                }
                float p[16];
#pragma unroll
                for (int r = 0; r < 16; ++r) p[r] = EXP2F(sa[r] + sb[r]);
#pragma unroll
                for (int r = 0; r < 16; ++r) lacc += p[r];
                unsigned int pk[8], px[8];
#pragma unroll
                for (int t = 0; t < 8; ++t) pk[t] = pack_bf2_ru(p[2 * t], p[2 * t + 1]);
#pragma unroll
                for (int t = 0; t < 8; ++t) px[t] = (unsigned int)__shfl_xor((int)pk[t], 32);
                union { v4u u; v8bf bb; } f0, f1;
                if (hi == 0) {
                    f0.u = (v4u){pk[0], pk[1], px[0], px[1]};
                    f1.u = (v4u){pk[4], pk[5], px[4], px[5]};
                } else {
                    f0.u = (v4u){px[2], px[3], pk[2], pk[3]};
                    f1.u = (v4u){px[6], px[7], pk[6], pk[7]};
                }
                // frag-tile (qsub=pi, kf=kt*2+{0,1}); unit lane-major -> conflict-free b128
                unsigned short* pw_ = PuS + buf * 4096 + (pi * 4 + kt * 2) * 512 + (hi * 32 + l31) * 8;
                *(v4u*)pw_ = f0.u;
                *(v4u*)(pw_ + 512) = f1.u;
            }
            WAIT_VM0();                                      // DMA(i+1) landed before next round
        }
        if (!isP && it > 0) {
            // ================= CONSUMER round i: PV over tile it-1 =================
            const int pbuf = (it - 1) & 1;
            const unsigned short* pb = PuS + pbuf * 4096 + (hi * 32 + l31) * 8;
#pragma unroll
            for (int qt = 0; qt < 2; ++qt) {
                v8bf bp[4];
#pragma unroll
                for (int kf = 0; kf < 4; ++kf)
                    bp[kf] = *(const v8bf*)(pb + (qt * 4 + kf) * 512);
#pragma unroll
                for (int kf = 0; kf < 4; ++kf)
#pragma unroll
                    for (int ct = 0; ct < 4; ++ct)
                        o[ct][qt] = __builtin_amdgcn_mfma_f32_32x32x16_bf16(av[ct][kf], bp[kf], o[ct][qt], 0, 0, 0);
            }
            // reload V frags for tile it (consumed next round; ~1 round slack)
            const size_t kc0 = (size_t)(it & 63) * 64;
#pragma unroll
            for (int ct = 0; ct < 4; ++ct)
#pragma unroll
                for (int kf = 0; kf < 4; ++kf)
                    av[ct][kf] = *(const v8bf*)(vbase[ct] + kc0 + kf * 16);
        }
        BARRIER_LDS();                                       // single per-round barrier
    }

    // ---- row-sum handoff: producers -> lsum -> consumers
    if (isP) {
        float tot = lacc + __shfl_xor(lacc, 32);
        if (hi == 0) lsumF[pi * 32 + l31] = tot;
    }
    BARRIER_LDS();
    if (!isP) {
        float inv[2];
#pragma unroll
        for (int qt = 0; qt < 2; ++qt) inv[qt] = 1.0f / lsumF[qt * 32 + l31];
        // store: O^T C/D lane = q-col -> coalesced dwords
#pragma unroll
        for (int ct = 0; ct < 4; ++ct)
#pragma unroll
            for (int qt = 0; qt < 2; ++qt) {
                float* ob = out + (size_t)b * NC * NHW + qt64 + qt * 32 + l31;
#pragma unroll
                for (int r = 0; r < 16; ++r) {
                    int c = pi * 128 + ct * 32 + (r & 3) + 8 * (r >> 2) + 4 * hi;
                    ob[(size_t)c * NHW] = o[ct][qt][r] * inv[qt];
                }
            }
    }
}

extern "C" void kernel_launch(void* const* d_in, const int* in_sizes, int n_in,
                              void* d_out, int out_size, void* d_ws, size_t ws_size,
                              hipStream_t stream) {
    const float* l  = (const float*)d_in[0];
    const float* wt = (const float*)d_in[1];
    const float* wp = (const float*)d_in[2];
    float* out = (float*)d_out;

    char* ws = (char*)d_ws;
    unsigned short* Wbf = (unsigned short*)ws;                          // 131072 B
    unsigned short* Qbf = (unsigned short*)(ws + 131072);               // 8 MB
    unsigned short* Kbf = (unsigned short*)(ws + 131072 + 8388608);     // 8 MB (pre-swizzled)
    unsigned short* Vbf = (unsigned short*)(ws + 131072 + 16777216);    // 16 MB

    hipLaunchKernelGGL(cast_w_kernel, dim3(256), dim3(256), 0, stream, wt, wp, Wbf);
    hipLaunchKernelGGL(proj_kernel,   dim3(512), dim3(256), 0, stream, l, Wbf, Qbf, Kbf, Vbf);
    hipLaunchKernelGGL(attn_kernel,   dim3(512), dim3(256), 0, stream, Qbf, Kbf, Vbf, out);
}

// Round 12
// 251.587 us; speedup vs baseline: 2.0121x; 2.0121x over previous
//
#include <hip/hip_runtime.h>
#include <stdint.h>

#define NB 8
#define NC 256
#define NE 128
#define NHW 4096

typedef __bf16 v8bf __attribute__((ext_vector_type(8)));
typedef float v4f __attribute__((ext_vector_type(4)));
typedef float v16f __attribute__((ext_vector_type(16)));
typedef unsigned int v4u __attribute__((ext_vector_type(4)));

typedef unsigned int __attribute__((address_space(1))) uint_g;
typedef unsigned int __attribute__((address_space(3))) uint_l;

#if __has_builtin(__builtin_amdgcn_exp2f)
#define EXP2F(x) __builtin_amdgcn_exp2f(x)
#else
#define EXP2F(x) exp2f(x)
#endif

// LDS-only barrier: drains lgkmcnt but NOT vmcnt (global prefetch/DMA stays in flight)
#define BARRIER_LDS() asm volatile("s_waitcnt lgkmcnt(0)\n\ts_barrier" ::: "memory")
#define WAIT_VM0()    asm volatile("s_waitcnt vmcnt(0)" ::: "memory")

// async global->LDS DMA, 16B per lane: LDS dst = uniform base + lane*16
__device__ __forceinline__ void dma16(const unsigned short* g, unsigned short* l) {
    __builtin_amdgcn_global_load_lds((const uint_g*)g, (uint_l*)l, 16, 0, 0);
}

// fp32 -> bf16 round-to-nearest-even
__device__ __forceinline__ unsigned short f2bf(float x) {
    union { float f; unsigned int u; } v; v.f = x;
    unsigned int r = v.u + 0x7fffu + ((v.u >> 16) & 1u);
    return (unsigned short)(r >> 16);
}

// pack two fp32 -> bf16x2, round-half-up (P in (0,1], R4-verified accuracy)
__device__ __forceinline__ unsigned int pack_bf2_ru(float a, float b) {
    union { float f; unsigned int u; } va, vb; va.f = a; vb.f = b;
    return ((va.u + 0x8000u) >> 16) | ((vb.u + 0x8000u) & 0xffff0000u);
}

// ---------------- K0: cast weights. Wbf[e][c], e<128 = w_theta*(scale*log2e), e>=128 = w_phi
__global__ __launch_bounds__(256) void cast_w_kernel(const float* __restrict__ wt,
                                                     const float* __restrict__ wp,
                                                     unsigned short* __restrict__ Wbf) {
    int i = blockIdx.x * 256 + threadIdx.x;
    const float QS = 0.08838834764831845f * 1.4426950408889634f;
    float v = (i < 32768) ? wt[i] * QS : wp[i - 32768];
    Wbf[i] = f2bf(v);
}

// ---------------- K1: projection (+ fused V cast). K stored PRE-SWIZZLED
// (16B unit u -> u ^ (row&15) within each row) so attn's DMA'd LDS tile is
// conflict-free under the R5-verified fragment reads. Q unswizzled.
__global__ __launch_bounds__(256, 2) void proj_kernel(const float* __restrict__ l,
                                                      const unsigned short* __restrict__ Wbf,
                                                      unsigned short* __restrict__ Qbf,
                                                      unsigned short* __restrict__ Kbf,
                                                      unsigned short* __restrict__ Vbf) {
    __shared__ __align__(16) unsigned short A[64][264];
    __shared__ __align__(16) unsigned short Ost[2][32][136];
    const int tid = threadIdx.x;
    const int b = blockIdx.x & 7;
    const int qt = (blockIdx.x >> 3) << 6;
    const float* lb = l + ((size_t)b * NC * NHW + qt);

    for (int s = 0; s < 16; ++s) {
        int f = tid + s * 256;
        int c = f >> 4, j = f & 15;
        float4 v = *(const float4*)(lb + (size_t)c * NHW + j * 4);
        ushort4 o4;
        o4.x = f2bf(v.x); o4.y = f2bf(v.y); o4.z = f2bf(v.z); o4.w = f2bf(v.w);
        A[j * 4 + 0][c] = o4.x;
        A[j * 4 + 1][c] = o4.y;
        A[j * 4 + 2][c] = o4.z;
        A[j * 4 + 3][c] = o4.w;
        *(ushort4*)(Vbf + (size_t)b * NC * NHW + (size_t)c * NHW + qt + j * 4) = o4;
    }
    __syncthreads();

    const int w = tid >> 6, L = tid & 63;
    const int l15 = L & 15, q4 = L >> 4;
    const v4f vz = {0.f, 0.f, 0.f, 0.f};
    v4f acc[4][4];
    for (int mt = 0; mt < 4; ++mt)
        for (int nt = 0; nt < 4; ++nt) acc[mt][nt] = vz;

    for (int kf = 0; kf < 8; ++kf) {
        int kc = kf * 32 + q4 * 8;
        v8bf a[4], bb[4];
        for (int mt = 0; mt < 4; ++mt)
            a[mt] = *(const v8bf*)&A[mt * 16 + l15][kc];
        for (int nt = 0; nt < 4; ++nt)
            bb[nt] = *(const v8bf*)(Wbf + (w * 64 + nt * 16 + l15) * 256 + kc);
        for (int mt = 0; mt < 4; ++mt)
            for (int nt = 0; nt < 4; ++nt)
                acc[mt][nt] = __builtin_amdgcn_mfma_f32_16x16x32_bf16(a[mt], bb[nt], acc[mt][nt], 0, 0, 0);
    }

    const int side = w >> 1;
    const int ebase = (w & 1) * 64;
#pragma unroll
    for (int ph = 0; ph < 2; ++ph) {
        __syncthreads();
#pragma unroll
        for (int mh = 0; mh < 2; ++mh) {
            int mt = ph * 2 + mh;
#pragma unroll
            for (int nt = 0; nt < 4; ++nt)
#pragma unroll
                for (int r = 0; r < 4; ++r) {
                    int q32 = mh * 16 + q4 * 4 + r;
                    Ost[side][q32][ebase + nt * 16 + l15] = f2bf(acc[mt][nt][r]);
                }
        }
        __syncthreads();
#pragma unroll
        for (int s = 0; s < 4; ++s) {
            int idx = tid + s * 256;
            int sd = idx >> 9, rem = idx & 511;
            int r32 = rem >> 4, c8 = rem & 15;
            unsigned short* dst = sd ? Kbf : Qbf;
            int c8s = sd ? (c8 ^ (r32 & 15)) : c8;   // pre-swizzle K only
            *(uint4*)(dst + ((size_t)b * NHW + qt + ph * 32 + r32) * NE + c8s * 8) =
                *(const uint4*)&Ost[sd][r32][c8 * 8];
        }
    }
}

// ---------------- K2: flash attention, producer/consumer, 2 DECOUPLED blocks/CU.
// R11 structure with the REGISTER BUDGET fixed: consumer streams V in two
// half-round batches (a0/a1 = 32 VGPR, reused) instead of 64 resident VGPRs,
// single V base pointer instead of vbase[4]. Union of producer (bq 32) and
// consumer (~70) residents + 128 AGPR fits 256 -> no scratch spill (R11's
// WRITE_SIZE 285MB alarm). Everything else identical to R11 (Pu stride 4096).
// Block 256 thr = 4 waves (2P + 2C), q-tile 64, k-tile 64, grid 512 -> 2
// blocks/CU with independent barrier domains; roles XORed by (blockIdx>>8)&1.
// LDS 48.3K: Ku dbuf 32K | Pu dbuf 16K | lsum 256B. 1 LDS-only barrier/round.
__global__ __launch_bounds__(256, 2) void attn_kernel(const unsigned short* __restrict__ Qbf,
                                                      const unsigned short* __restrict__ Kbf,
                                                      const unsigned short* __restrict__ Vbf,
                                                      float* __restrict__ out) {
    __shared__ __align__(16) unsigned char smem[49408];
    unsigned short* KuS = (unsigned short*)smem;             // 2 x 16KB swizzled K tiles
    unsigned short* PuS = (unsigned short*)(smem + 32768);   // 2 bufs x 8 frag-tiles x 1KB
    float* lsumF = (float*)(smem + 49152);                   // [2][32]

    const int tid = threadIdx.x;
    const int b = blockIdx.x & 7;                            // batch -> XCD affinity
    const int qt64 = (blockIdx.x >> 3) << 6;
    const int w = tid >> 6;
    const int L = tid & 63;
    const int l31 = L & 31, hi = L >> 5;
    const int x15 = l31 & 15;
    const int rw = w ^ (((blockIdx.x >> 8) & 1) << 1);       // role-mix co-resident blocks
    const bool isP = rw < 2;
    const int pi = rw & 1;                                   // producer q-slice / consumer c-half

    const unsigned short* Kb = Kbf + (size_t)b * NHW * NE;
    const unsigned short* Vb = Vbf + (size_t)b * NC * NHW;

    v16f o[4][2];                                            // consumer acc [ct][qt], 128 AGPR
#pragma unroll
    for (int ct = 0; ct < 4; ++ct)
#pragma unroll
        for (int qt = 0; qt < 2; ++qt)
#pragma unroll
            for (int r = 0; r < 16; ++r) o[ct][qt][r] = 0.f;
    float lacc = 0.f;                                        // producer row-sum partial

    v8bf bq[8];                                              // producer Q B-frags
    // consumer single V base (2 regs); frag addr = vb + ct*32*NHW + kc + kf*16
    const unsigned short* vb = Vb + (size_t)(pi * 128 + l31) * NHW + hi * 8;

    if (isP) {
        // producer prologue: Q frags + DMA K tile 0 into buf 0 (8 x 1KB per wave)
        const unsigned short* qrow = Qbf + ((size_t)b * NHW + qt64 + pi * 32 + l31) * NE + hi * 8;
#pragma unroll
        for (int ef = 0; ef < 8; ++ef)
            bq[ef] = *(const v8bf*)(qrow + ef * 16);
#pragma unroll
        for (int jj = 0; jj < 8; ++jj) {
            int j = pi * 8 + jj;
            dma16(Kb + (size_t)j * 512 + L * 8, KuS + j * 512);
        }
        WAIT_VM0();
    }
    BARRIER_LDS();

    for (int it = 0; it < 65; ++it) {
        if (isP && it < 64) {
            // ================= PRODUCER round i =================
            const int buf = it & 1;
            const int nbuf = (it + 1) & 1;
            const size_t ktn = (size_t)((it + 1) & 63) * 64;
#pragma unroll
            for (int jj = 0; jj < 8; ++jj) {
                int j = pi * 8 + jj;
                dma16(Kb + ktn * NE + (size_t)j * 512 + L * 8, KuS + nbuf * 8192 + j * 512);
            }
            const unsigned short* kub = KuS + buf * 8192;
#pragma unroll
            for (int kt = 0; kt < 2; ++kt) {
                v16f sa, sb;
#pragma unroll
                for (int r = 0; r < 16; ++r) { sa[r] = 0.f; sb[r] = 0.f; }
                const unsigned short* krow = kub + (kt * 32 + l31) * 128;
#pragma unroll
                for (int ef = 0; ef < 4; ++ef) {
                    v8bf ak0 = *(const v8bf*)(krow + (((2 * ef + hi) ^ x15) * 8));
                    v8bf ak1 = *(const v8bf*)(krow + (((2 * (ef + 4) + hi) ^ x15) * 8));
                    sa = __builtin_amdgcn_mfma_f32_32x32x16_bf16(ak0, bq[ef], sa, 0, 0, 0);
                    sb = __builtin_amdgcn_mfma_f32_32x32x16_bf16(ak1, bq[ef + 4], sb, 0, 0, 0);
                }
                float p[16];
#pragma unroll
                for (int r = 0; r < 16; ++r) p[r] = EXP2F(sa[r] + sb[r]);
#pragma unroll
                for (int r = 0; r < 16; ++r) lacc += p[r];
                unsigned int pk[8], px[8];
#pragma unroll
                for (int t = 0; t < 8; ++t) pk[t] = pack_bf2_ru(p[2 * t], p[2 * t + 1]);
#pragma unroll
                for (int t = 0; t < 8; ++t) px[t] = (unsigned int)__shfl_xor((int)pk[t], 32);
                union { v4u u; v8bf bb; } f0, f1;
                if (hi == 0) {
                    f0.u = (v4u){pk[0], pk[1], px[0], px[1]};
                    f1.u = (v4u){pk[4], pk[5], px[4], px[5]};
                } else {
                    f0.u = (v4u){px[2], px[3], pk[2], pk[3]};
                    f1.u = (v4u){px[6], px[7], pk[6], pk[7]};
                }
                // frag-tile (qsub=pi, kf=kt*2+{0,1}); unit lane-major -> conflict-free b128
                unsigned short* pw_ = PuS + buf * 4096 + (pi * 4 + kt * 2) * 512 + (hi * 32 + l31) * 8;
                *(v4u*)pw_ = f0.u;
                *(v4u*)(pw_ + 512) = f1.u;
            }
            WAIT_VM0();                                      // DMA(i+1) landed before next round
        }
        if (!isP && it > 0) {
            // ============ CONSUMER round i: PV over tile it-1, V streamed ============
            const int pbuf = (it - 1) & 1;
            const size_t kc = (size_t)((it - 1) & 63) * 64;
            const unsigned short* pb = PuS + pbuf * 4096 + (hi * 32 + l31) * 8;
            v8bf bp0[4], bp1[4];
#pragma unroll
            for (int kf = 0; kf < 4; ++kf) {
                bp0[kf] = *(const v8bf*)(pb + kf * 512);
                bp1[kf] = *(const v8bf*)(pb + (4 + kf) * 512);
            }
            // half 1: kf = 0,1 (a regs reused for half 2)
            v8bf a0[4], a1[4];
#pragma unroll
            for (int ct = 0; ct < 4; ++ct) {
                const unsigned short* vr = vb + (size_t)ct * 32 * NHW + kc;
                a0[ct] = *(const v8bf*)(vr);
                a1[ct] = *(const v8bf*)(vr + 16);
            }
#pragma unroll
            for (int ct = 0; ct < 4; ++ct) {
                o[ct][0] = __builtin_amdgcn_mfma_f32_32x32x16_bf16(a0[ct], bp0[0], o[ct][0], 0, 0, 0);
                o[ct][1] = __builtin_amdgcn_mfma_f32_32x32x16_bf16(a0[ct], bp1[0], o[ct][1], 0, 0, 0);
            }
#pragma unroll
            for (int ct = 0; ct < 4; ++ct) {
                o[ct][0] = __builtin_amdgcn_mfma_f32_32x32x16_bf16(a1[ct], bp0[1], o[ct][0], 0, 0, 0);
                o[ct][1] = __builtin_amdgcn_mfma_f32_32x32x16_bf16(a1[ct], bp1[1], o[ct][1], 0, 0, 0);
            }
            // half 2: kf = 2,3
#pragma unroll
            for (int ct = 0; ct < 4; ++ct) {
                const unsigned short* vr = vb + (size_t)ct * 32 * NHW + kc;
                a0[ct] = *(const v8bf*)(vr + 32);
                a1[ct] = *(const v8bf*)(vr + 48);
            }
#pragma unroll
            for (int ct = 0; ct < 4; ++ct) {
                o[ct][0] = __builtin_amdgcn_mfma_f32_32x32x16_bf16(a0[ct], bp0[2], o[ct][0], 0, 0, 0);
                o[ct][1] = __builtin_amdgcn_mfma_f32_32x32x16_bf16(a0[ct], bp1[2], o[ct][1], 0, 0, 0);
            }
#pragma unroll
            for (int ct = 0; ct < 4; ++ct) {
                o[ct][0] = __builtin_amdgcn_mfma_f32_32x32x16_bf16(a1[ct], bp0[3], o[ct][0], 0, 0, 0);
                o[ct][1] = __builtin_amdgcn_mfma_f32_32x32x16_bf16(a1[ct], bp1[3], o[ct][1], 0, 0, 0);
            }
        }
        BARRIER_LDS();                                       // single per-round barrier
    }

    // ---- row-sum handoff: producers -> lsum -> consumers
    if (isP) {
        float tot = lacc + __shfl_xor(lacc, 32);
        if (hi == 0) lsumF[pi * 32 + l31] = tot;
    }
    BARRIER_LDS();
    if (!isP) {
        float inv[2];
#pragma unroll
        for (int qt = 0; qt < 2; ++qt) inv[qt] = 1.0f / lsumF[qt * 32 + l31];
        // store: O^T C/D lane = q-col -> coalesced dwords
#pragma unroll
        for (int ct = 0; ct < 4; ++ct)
#pragma unroll
            for (int qt = 0; qt < 2; ++qt) {
                float* ob = out + (size_t)b * NC * NHW + qt64 + qt * 32 + l31;
#pragma unroll
                for (int r = 0; r < 16; ++r) {
                    int c = pi * 128 + ct * 32 + (r & 3) + 8 * (r >> 2) + 4 * hi;
                    ob[(size_t)c * NHW] = o[ct][qt][r] * inv[qt];
                }
            }
    }
}

extern "C" void kernel_launch(void* const* d_in, const int* in_sizes, int n_in,
                              void* d_out, int out_size, void* d_ws, size_t ws_size,
                              hipStream_t stream) {
    const float* l  = (const float*)d_in[0];
    const float* wt = (const float*)d_in[1];
    const float* wp = (const float*)d_in[2];
    float* out = (float*)d_out;

    char* ws = (char*)d_ws;
    unsigned short* Wbf = (unsigned short*)ws;                          // 131072 B
    unsigned short* Qbf = (unsigned short*)(ws + 131072);               // 8 MB
    unsigned short* Kbf = (unsigned short*)(ws + 131072 + 8388608);     // 8 MB (pre-swizzled)
    unsigned short* Vbf = (unsigned short*)(ws + 131072 + 16777216);    // 16 MB

    hipLaunchKernelGGL(cast_w_kernel, dim3(256), dim3(256), 0, stream, wt, wp, Wbf);
    hipLaunchKernelGGL(proj_kernel,   dim3(512), dim3(256), 0, stream, l, Wbf, Qbf, Kbf, Vbf);
    hipLaunchKernelGGL(attn_kernel,   dim3(512), dim3(256), 0, stream, Qbf, Kbf, Vbf, out);
}